// Round 9
// baseline (2004.627 us; speedup 1.0000x reference)
//
#include <hip/hip_runtime.h>
#include <math.h>

#define NT 256     // block size for small kernels
#define NTS 512    // sage_layer block: 8 waves, 64 nodes, 48KB LDS
#define KN 64      // nodes per sage block

__device__ __forceinline__ float rlf(float v, int l) {
    return __int_as_float(__builtin_amdgcn_readlane(__float_as_int(v), l));
}
__device__ __forceinline__ int imax(int a, int b) { return a > b ? a : b; }

// ---------------- CSR build ----------------

__global__ void zero_i32(int* __restrict__ p, int n) {
    int t = blockIdx.x * blockDim.x + threadIdx.x;
    if (t < n) p[t] = 0;
}

__global__ void hist_dst(int* __restrict__ cnt, const int* __restrict__ dst, int n_edges) {
    int e = blockIdx.x * blockDim.x + threadIdx.x;
    if (e < n_edges) atomicAdd(&cnt[dst[e]], 1);
}

// single-block exclusive scan of cnt[0..n) -> row_off[0..n], cursor[0..n)
__global__ void scan_offsets(const int* __restrict__ cnt, int* __restrict__ row_off,
                             int* __restrict__ cursor, int n) {
    __shared__ int tsum[1024];
    int tid = threadIdx.x;
    int chunk = (n + 1023) / 1024;
    int beg = tid * chunk;
    int end = beg + chunk; if (end > n) end = n;
    int s = 0;
    for (int i = beg; i < end; ++i) s += cnt[i];
    tsum[tid] = s;
    __syncthreads();
    for (int off = 1; off < 1024; off <<= 1) {
        int v = (tid >= off) ? tsum[tid - off] : 0;
        __syncthreads();
        tsum[tid] += v;
        __syncthreads();
    }
    int run = (tid == 0) ? 0 : tsum[tid - 1];
    for (int i = beg; i < end; ++i) {
        row_off[i] = run;
        cursor[i] = run;
        run += cnt[i];
    }
    if (tid == 1023) row_off[n] = tsum[1023];
}

// scatter (src,dst) pairs into dst-sorted CSR order
__global__ void edge_scatter(int2* __restrict__ csr_sd, int* __restrict__ cursor,
                             const int* __restrict__ src, const int* __restrict__ dst,
                             int n_edges) {
    int e = blockIdx.x * blockDim.x + threadIdx.x;
    if (e < n_edges) {
        int d = dst[e];
        int p = atomicAdd(&cursor[d], 1);
        csr_sd[p] = make_int2(src[e], d);
    }
}

// ---------------- pooling helpers ----------------

__global__ void pool_init(float* __restrict__ pooled, int n) {
    int t = blockIdx.x * blockDim.x + threadIdx.x;
    if (t < n) pooled[t] = -INFINITY;
}

__device__ __forceinline__ void atomicMaxFloat(float* addr, float value) {
    if (value >= 0.0f)
        atomicMax((int*)addr, __float_as_int(value));
    else
        atomicMin((unsigned int*)addr, (unsigned int)__float_as_int(value));
}

// ---------------- fused SAGE layer (edge-parallel aggregation) ----------------
// Block owns KN=64 consecutive nodes. Phase 1: waves sweep the node range's
// CSR edge span edge-per-wave-slot, unroll 4: coalesced 256B gather of
// h_in[src] + ds_add_f32 into AGG[dst-n0] (LDS). No readlane chains, no
// per-wave neighbor-list walk -> latency hidden by 24 waves/CU x 4-deep ILP.
// Phase 2: dense update (r4-proven quad structure) from LDS means.
__global__ __launch_bounds__(NTS, 6) void sage_layer(
    float* __restrict__ out, float* __restrict__ pooled,
    const float* __restrict__ h_in,
    const int* __restrict__ row_off, const int2* __restrict__ csr_sd,
    const int* __restrict__ batch,
    const float* __restrict__ Wl, const float* __restrict__ Wr,
    const float* __restrict__ bl,
    int n_nodes, int do_pool) {
    __shared__ float WL[4096];  // WL[k4*256 + f*4 + kk] = Wl[f][k4*4+kk]
    __shared__ float WR[4096];
    __shared__ float AGG[KN * 64];
    int tid = threadIdx.x;
    for (int t = tid; t < 4096; t += NTS) {
        int kk = t & 3, f = (t >> 2) & 63, k4 = t >> 8;
        WL[t] = Wl[f * 64 + k4 * 4 + kk];
        WR[t] = Wr[f * 64 + k4 * 4 + kk];
        AGG[t] = 0.0f;
    }
    __syncthreads();

    int lane = tid & 63;
    int w = tid >> 6;  // wave id 0..7
    int n0 = blockIdx.x * KN;
    int n1 = n0 + KN; if (n1 > n_nodes) n1 = n_nodes;

    // ---- phase 1: edge-parallel gather-accumulate ----
    int eb = row_off[n0];
    int ee = row_off[n1];
    for (int e = eb + w * 4; e < ee; e += NTS / 64 * 4) {
        int ne = ee - e;  // >= 1
        int2 sd0 = csr_sd[e];
        int2 sd1 = csr_sd[e + (1 < ne ? 1 : 0)];
        int2 sd2 = csr_sd[e + (2 < ne ? 2 : 0)];
        int2 sd3 = csr_sd[e + (3 < ne ? 3 : 0)];
        float v0 = h_in[(size_t)sd0.x * 64 + lane];
        float v1 = h_in[(size_t)sd1.x * 64 + lane];
        float v2 = h_in[(size_t)sd2.x * 64 + lane];
        float v3 = h_in[(size_t)sd3.x * 64 + lane];
        atomicAdd(&AGG[(sd0.y - n0) * 64 + lane], v0);
        if (1 < ne) atomicAdd(&AGG[(sd1.y - n0) * 64 + lane], v1);
        if (2 < ne) atomicAdd(&AGG[(sd2.y - n0) * 64 + lane], v2);
        if (3 < ne) atomicAdd(&AGG[(sd3.y - n0) * 64 + lane], v3);
    }
    __syncthreads();

    // ---- phase 2: dense update, 8 nodes per wave as 2 quads ----
    for (int qq = 0; qq < 2; ++qq) {
        int base = n0 + w * 8 + qq * 4;

        float mean0 = 0.f, mean1 = 0.f, mean2 = 0.f, mean3 = 0.f;
        float hv0 = 0.f, hv1 = 0.f, hv2 = 0.f, hv3 = 0.f;
#define LOAD_NODE(MEAN, HV, N)                                                \
        {                                                                     \
            int i = base + (N);                                               \
            if (i < n_nodes) {                                                \
                int deg = row_off[i + 1] - row_off[i];                        \
                MEAN = AGG[(i - n0) * 64 + lane] *                            \
                       (1.0f / (float)imax(deg, 1));                          \
                HV = h_in[(size_t)i * 64 + lane];                             \
            }                                                                 \
        }
        LOAD_NODE(mean0, hv0, 0)
        LOAD_NODE(mean1, hv1, 1)
        LOAD_NODE(mean2, hv2, 2)
        LOAD_NODE(mean3, hv3, 3)
#undef LOAD_NODE

        float bias = bl[lane];
        float o0 = bias, o1 = bias, o2 = bias, o3 = bias;
        for (int k4 = 0; k4 < 16; ++k4) {
            float4 wl = *(const float4*)&WL[k4 * 256 + lane * 4];
            float4 wr = *(const float4*)&WR[k4 * 256 + lane * 4];
            int kb = k4 * 4;
#define DENSE_KK(WLK, WRK, KK)                                                \
            {                                                                 \
                int k = kb + (KK);                                            \
                o0 += rlf(mean0, k) * (WLK) + rlf(hv0, k) * (WRK);            \
                o1 += rlf(mean1, k) * (WLK) + rlf(hv1, k) * (WRK);            \
                o2 += rlf(mean2, k) * (WLK) + rlf(hv2, k) * (WRK);            \
                o3 += rlf(mean3, k) * (WLK) + rlf(hv3, k) * (WRK);            \
            }
            DENSE_KK(wl.x, wr.x, 0)
            DENSE_KK(wl.y, wr.y, 1)
            DENSE_KK(wl.z, wr.z, 2)
            DENSE_KK(wl.w, wr.w, 3)
#undef DENSE_KK
        }

        o0 = tanhf(o0); o1 = tanhf(o1); o2 = tanhf(o2); o3 = tanhf(o3);

#define WRITE_NODE(O, N)                                                      \
        {                                                                     \
            int i = base + (N);                                               \
            if (i < n_nodes) {                                                \
                if (do_pool) {                                                \
                    atomicMaxFloat(&pooled[(size_t)batch[i] * 64 + lane], O); \
                } else {                                                      \
                    out[(size_t)i * 64 + lane] = O;                           \
                }                                                             \
            }                                                                 \
        }
        WRITE_NODE(o0, 0)
        WRITE_NODE(o1, 1)
        WRITE_NODE(o2, 2)
        WRITE_NODE(o3, 3)
#undef WRITE_NODE
    }
}

// ---------------- MLP head ----------------
__global__ void head(float* __restrict__ out, const float* __restrict__ pooled,
                     const float* __restrict__ W1, const float* __restrict__ b1,
                     const float* __restrict__ W2, const float* __restrict__ b2) {
    __shared__ float W1T[64][64];
    int tid = threadIdx.x;
    for (int t = tid; t < 4096; t += NT) {
        int f = t >> 6, k = t & 63;
        W1T[k][f] = W1[t];
    }
    __syncthreads();

    int lane = tid & 63;
    int g = blockIdx.x * (NT >> 6) + (tid >> 6);
    float v = pooled[(size_t)g * 64 + lane];
    float bias = b1[lane];
#pragma unroll
    for (int it = 0; it < 3; ++it) {
        float acc = bias;
#pragma unroll
        for (int k = 0; k < 64; ++k) {
            acc += rlf(v, k) * W1T[k][lane];
        }
        v = tanhf(acc);
    }
#pragma unroll
    for (int j = 0; j < 3; ++j) {
        float p = v * W2[j * 64 + lane];
#pragma unroll
        for (int off = 32; off >= 1; off >>= 1) p += __shfl_xor(p, off);
        if (lane == 0) out[g * 3 + j] = p + b2[j];
    }
}

// ---------------- launch ----------------

extern "C" void kernel_launch(void* const* d_in, const int* in_sizes, int n_in,
                              void* d_out, int out_size, void* d_ws, size_t ws_size,
                              hipStream_t stream) {
    const float* x   = (const float*)d_in[0];
    const float* Wl0 = (const float*)d_in[1];
    const float* Wr0 = (const float*)d_in[2];
    const float* bl0 = (const float*)d_in[3];
    const float* Wl  = (const float*)d_in[4];
    const float* Wr  = (const float*)d_in[5];
    const float* bl  = (const float*)d_in[6];
    const float* W1  = (const float*)d_in[7];
    const float* b1  = (const float*)d_in[8];
    const float* W2  = (const float*)d_in[9];
    const float* b2  = (const float*)d_in[10];
    const int* ei    = (const int*)d_in[11];
    const int* batch = (const int*)d_in[12];

    int n_nodes = in_sizes[0] / 64;
    int n_edges = in_sizes[11] / 2;
    const int* src = ei;
    const int* dst = ei + n_edges;

    float* bufA   = (float*)d_ws;                          // n_nodes*64
    float* bufB   = bufA + (size_t)n_nodes * 64;           // n_nodes*64
    int2* csr_sd  = (int2*)(bufB + (size_t)n_nodes * 64);  // n_edges int2
    int* row_off  = (int*)(csr_sd + n_edges);              // n_nodes+1
    int* cursor   = row_off + (n_nodes + 1);               // n_nodes
    int* cnt      = cursor + n_nodes;                      // n_nodes
    float* pooled = (float*)(cnt + n_nodes);               // 128*64

    int eblk = (n_edges + NT - 1) / NT;
    int nblk = (n_nodes + NT - 1) / NT;
    int sage_blk = (n_nodes + KN - 1) / KN;  // 782 blocks ~ 3/CU

    // CSR build
    zero_i32<<<nblk, NT, 0, stream>>>(cnt, n_nodes);
    hist_dst<<<eblk, NT, 0, stream>>>(cnt, dst, n_edges);
    scan_offsets<<<1, 1024, 0, stream>>>(cnt, row_off, cursor, n_nodes);
    edge_scatter<<<eblk, NT, 0, stream>>>(csr_sd, cursor, src, dst, n_edges);

    pool_init<<<(128 * 64 + NT - 1) / NT, NT, 0, stream>>>(pooled, 128 * 64);

    sage_layer<<<sage_blk, NTS, 0, stream>>>(bufA, pooled, x, row_off, csr_sd, batch,
                                             Wl0, Wr0, bl0, n_nodes, 0);
    sage_layer<<<sage_blk, NTS, 0, stream>>>(bufB, pooled, bufA, row_off, csr_sd, batch,
                                             Wl, Wr, bl, n_nodes, 0);
    sage_layer<<<sage_blk, NTS, 0, stream>>>(bufA, pooled, bufB, row_off, csr_sd, batch,
                                             Wl, Wr, bl, n_nodes, 0);
    sage_layer<<<sage_blk, NTS, 0, stream>>>(bufB, pooled, bufA, row_off, csr_sd, batch,
                                             Wl, Wr, bl, n_nodes, 1);

    head<<<32, NT, 0, stream>>>((float*)d_out, pooled, W1, b1, W2, b2);
}

// Round 10
// 563.266 us; speedup vs baseline: 3.5589x; 3.5589x over previous
//
#include <hip/hip_runtime.h>
#include <math.h>

#define NT 256

__device__ __forceinline__ float rlf(float v, int l) {
    return __int_as_float(__builtin_amdgcn_readlane(__float_as_int(v), l));
}
__device__ __forceinline__ int rli(int v, int l) {
    return __builtin_amdgcn_readlane(v, l);
}

// ---------------- CSR build ----------------

__global__ void zero_i32(int* __restrict__ p, int n) {
    int t = blockIdx.x * blockDim.x + threadIdx.x;
    if (t < n) p[t] = 0;
}

__global__ void hist_dst(int* __restrict__ cnt, const int* __restrict__ dst, int n_edges) {
    int e = blockIdx.x * blockDim.x + threadIdx.x;
    if (e < n_edges) atomicAdd(&cnt[dst[e]], 1);
}

// single-block exclusive scan of cnt[0..n) -> row_off[0..n], cursor[0..n)
__global__ void scan_offsets(const int* __restrict__ cnt, int* __restrict__ row_off,
                             int* __restrict__ cursor, int n) {
    __shared__ int tsum[1024];
    int tid = threadIdx.x;
    int chunk = (n + 1023) / 1024;
    int beg = tid * chunk;
    int end = beg + chunk; if (end > n) end = n;
    int s = 0;
    for (int i = beg; i < end; ++i) s += cnt[i];
    tsum[tid] = s;
    __syncthreads();
    for (int off = 1; off < 1024; off <<= 1) {
        int v = (tid >= off) ? tsum[tid - off] : 0;
        __syncthreads();
        tsum[tid] += v;
        __syncthreads();
    }
    int run = (tid == 0) ? 0 : tsum[tid - 1];
    for (int i = beg; i < end; ++i) {
        row_off[i] = run;
        cursor[i] = run;
        run += cnt[i];
    }
    if (tid == 1023) row_off[n] = tsum[1023];
}

__global__ void edge_scatter(int* __restrict__ csr_src, int* __restrict__ cursor,
                             const int* __restrict__ src, const int* __restrict__ dst,
                             int n_edges) {
    int e = blockIdx.x * blockDim.x + threadIdx.x;
    if (e < n_edges) {
        int p = atomicAdd(&cursor[dst[e]], 1);
        csr_src[p] = src[e];
    }
}

// transpose weights into [k4][f][kk] layout: out[k4*256 + f*4 + kk] = W[f*64 + k4*4 + kk]
__global__ void wtrans(float* __restrict__ out, const float* __restrict__ W) {
    int t = blockIdx.x * blockDim.x + threadIdx.x;
    if (t < 4096) {
        int kk = t & 3, f = (t >> 2) & 63, k4 = t >> 8;
        out[t] = W[f * 64 + k4 * 4 + kk];
    }
}

// ---------------- pooling helpers ----------------

__global__ void pool_init(float* __restrict__ pooled, int n) {
    int t = blockIdx.x * blockDim.x + threadIdx.x;
    if (t < n) pooled[t] = -INFINITY;
}

__device__ __forceinline__ void atomicMaxFloat(float* addr, float value) {
    if (value >= 0.0f)
        atomicMax((int*)addr, __float_as_int(value));
    else
        atomicMin((unsigned int*)addr, (unsigned int)__float_as_int(value));
}

// ---------------- fused SAGE layer ----------------
// r4-proven structure: persistent waves, 4 nodes/wave-iter, 8-deep readlane
// gather, dense from WL in LDS (conflict-free ds_read_b128).
// Change vs r4: WR read from precomputed transposed GLOBAL (L1-resident,
// hidden under dense FMAs) -> LDS = 16KB -> 8 blocks/CU = 32 waves/CU.
// __launch_bounds__(256,8) caps VGPR at 64 >= the 44 r4 used (ILP preserved).
__global__ __launch_bounds__(NT, 8) void sage_layer(
    float* __restrict__ out, float* __restrict__ pooled,
    const float* __restrict__ h_in,
    const int* __restrict__ row_off, const int* __restrict__ csr_src,
    const int* __restrict__ batch,
    const float* __restrict__ Wl, const float* __restrict__ WrT,
    const float* __restrict__ bl,
    int n_nodes, int do_pool) {
    __shared__ float WL[4096];  // WL[k4*256 + f*4 + kk] = Wl[f][k4*4+kk]
    int tid = threadIdx.x;
    for (int t = tid; t < 4096; t += NT) {
        int kk = t & 3, f = (t >> 2) & 63, k4 = t >> 8;
        WL[t] = Wl[f * 64 + k4 * 4 + kk];
    }
    __syncthreads();

    int lane = tid & 63;
    int gwave = (blockIdx.x * NT + tid) >> 6;
    int nwaves = (gridDim.x * NT) >> 6;
    float bias = bl[lane];

    for (int q = gwave; q * 4 < n_nodes; q += nwaves) {
        int base = q * 4;
        float mean0 = 0.f, mean1 = 0.f, mean2 = 0.f, mean3 = 0.f;
        float hv0 = 0.f, hv1 = 0.f, hv2 = 0.f, hv3 = 0.f;

#define GATHER_NODE(MEAN, HV, N)                                              \
        {                                                                     \
            int i = base + (N);                                               \
            if (i < n_nodes) {                                                \
                int beg = row_off[i];                                         \
                int end_ = row_off[i + 1];                                    \
                int deg = end_ - beg;                                         \
                float a0 = 0.f, a1 = 0.f;                                     \
                for (int cb = beg; cb < end_; cb += 64) {                     \
                    int m = end_ - cb; if (m > 64) m = 64;                    \
                    int lidx = cb + (lane < m ? lane : m - 1);                \
                    int idx = csr_src[lidx];                                  \
                    for (int j = 0; j < m; j += 8) {                          \
                        int mm1 = m - 1;                                      \
                        int s0 = rli(idx, j);                                 \
                        int s1 = rli(idx, j + 1 < m ? j + 1 : mm1);           \
                        int s2 = rli(idx, j + 2 < m ? j + 2 : mm1);           \
                        int s3 = rli(idx, j + 3 < m ? j + 3 : mm1);           \
                        int s4 = rli(idx, j + 4 < m ? j + 4 : mm1);           \
                        int s5 = rli(idx, j + 5 < m ? j + 5 : mm1);           \
                        int s6 = rli(idx, j + 6 < m ? j + 6 : mm1);           \
                        int s7 = rli(idx, j + 7 < m ? j + 7 : mm1);           \
                        float v0 = h_in[s0 * 64 + lane];                      \
                        float v1 = h_in[s1 * 64 + lane];                      \
                        float v2 = h_in[s2 * 64 + lane];                      \
                        float v3 = h_in[s3 * 64 + lane];                      \
                        float v4 = h_in[s4 * 64 + lane];                      \
                        float v5 = h_in[s5 * 64 + lane];                      \
                        float v6 = h_in[s6 * 64 + lane];                      \
                        float v7 = h_in[s7 * 64 + lane];                      \
                        a0 += v0;                                             \
                        a1 += (j + 1 < m) ? v1 : 0.f;                         \
                        a0 += (j + 2 < m) ? v2 : 0.f;                         \
                        a1 += (j + 3 < m) ? v3 : 0.f;                         \
                        a0 += (j + 4 < m) ? v4 : 0.f;                         \
                        a1 += (j + 5 < m) ? v5 : 0.f;                         \
                        a0 += (j + 6 < m) ? v6 : 0.f;                         \
                        a1 += (j + 7 < m) ? v7 : 0.f;                         \
                    }                                                         \
                }                                                             \
                MEAN = (a0 + a1) * (1.0f / (float)(deg > 0 ? deg : 1));       \
                HV = h_in[(size_t)i * 64 + lane];                             \
            }                                                                 \
        }

        GATHER_NODE(mean0, hv0, 0)
        GATHER_NODE(mean1, hv1, 1)
        GATHER_NODE(mean2, hv2, 2)
        GATHER_NODE(mean3, hv3, 3)
#undef GATHER_NODE

        float o0 = bias, o1 = bias, o2 = bias, o3 = bias;
        for (int k4 = 0; k4 < 16; ++k4) {
            float4 wl = *(const float4*)&WL[k4 * 256 + lane * 4];
            float4 wr = *(const float4*)&WrT[k4 * 256 + lane * 4];
            int kb = k4 * 4;
#define DENSE_KK(WLK, WRK, KK)                                                \
            {                                                                 \
                int k = kb + (KK);                                            \
                o0 += rlf(mean0, k) * (WLK) + rlf(hv0, k) * (WRK);            \
                o1 += rlf(mean1, k) * (WLK) + rlf(hv1, k) * (WRK);            \
                o2 += rlf(mean2, k) * (WLK) + rlf(hv2, k) * (WRK);            \
                o3 += rlf(mean3, k) * (WLK) + rlf(hv3, k) * (WRK);            \
            }
            DENSE_KK(wl.x, wr.x, 0)
            DENSE_KK(wl.y, wr.y, 1)
            DENSE_KK(wl.z, wr.z, 2)
            DENSE_KK(wl.w, wr.w, 3)
#undef DENSE_KK
        }

        o0 = tanhf(o0); o1 = tanhf(o1); o2 = tanhf(o2); o3 = tanhf(o3);

#define WRITE_NODE(O, N)                                                      \
        {                                                                     \
            int i = base + (N);                                               \
            if (i < n_nodes) {                                                \
                if (do_pool) {                                                \
                    atomicMaxFloat(&pooled[(size_t)batch[i] * 64 + lane], O); \
                } else {                                                      \
                    out[(size_t)i * 64 + lane] = O;                           \
                }                                                             \
            }                                                                 \
        }
        WRITE_NODE(o0, 0)
        WRITE_NODE(o1, 1)
        WRITE_NODE(o2, 2)
        WRITE_NODE(o3, 3)
#undef WRITE_NODE
    }
}

// ---------------- MLP head ----------------
__global__ void head(float* __restrict__ out, const float* __restrict__ pooled,
                     const float* __restrict__ W1, const float* __restrict__ b1,
                     const float* __restrict__ W2, const float* __restrict__ b2) {
    __shared__ float W1T[64][64];
    int tid = threadIdx.x;
    for (int t = tid; t < 4096; t += NT) {
        int f = t >> 6, k = t & 63;
        W1T[k][f] = W1[t];
    }
    __syncthreads();

    int lane = tid & 63;
    int g = blockIdx.x * (NT >> 6) + (tid >> 6);
    float v = pooled[(size_t)g * 64 + lane];
    float bias = b1[lane];
#pragma unroll
    for (int it = 0; it < 3; ++it) {
        float acc = bias;
#pragma unroll
        for (int k = 0; k < 64; ++k) {
            acc += rlf(v, k) * W1T[k][lane];
        }
        v = tanhf(acc);
    }
#pragma unroll
    for (int j = 0; j < 3; ++j) {
        float p = v * W2[j * 64 + lane];
#pragma unroll
        for (int off = 32; off >= 1; off >>= 1) p += __shfl_xor(p, off);
        if (lane == 0) out[g * 3 + j] = p + b2[j];
    }
}

// ---------------- launch ----------------

extern "C" void kernel_launch(void* const* d_in, const int* in_sizes, int n_in,
                              void* d_out, int out_size, void* d_ws, size_t ws_size,
                              hipStream_t stream) {
    const float* x   = (const float*)d_in[0];
    const float* Wl0 = (const float*)d_in[1];
    const float* Wr0 = (const float*)d_in[2];
    const float* bl0 = (const float*)d_in[3];
    const float* Wl  = (const float*)d_in[4];
    const float* Wr  = (const float*)d_in[5];
    const float* bl  = (const float*)d_in[6];
    const float* W1  = (const float*)d_in[7];
    const float* b1  = (const float*)d_in[8];
    const float* W2  = (const float*)d_in[9];
    const float* b2  = (const float*)d_in[10];
    const int* ei    = (const int*)d_in[11];
    const int* batch = (const int*)d_in[12];

    int n_nodes = in_sizes[0] / 64;
    int n_edges = in_sizes[11] / 2;
    const int* src = ei;
    const int* dst = ei + n_edges;

    float* bufA   = (float*)d_ws;                         // n_nodes*64
    float* bufB   = bufA + (size_t)n_nodes * 64;          // n_nodes*64
    int* csr_src  = (int*)(bufB + (size_t)n_nodes * 64);  // n_edges
    int* row_off  = csr_src + n_edges;                    // n_nodes+1
    int* cursor   = row_off + (n_nodes + 1);              // n_nodes
    int* cnt      = cursor + n_nodes;                     // n_nodes
    float* pooled = (float*)(cnt + n_nodes);              // 128*64
    float* wr0t   = pooled + 128 * 64;                    // 4096
    float* wrt    = wr0t + 4096;                          // 4096

    int eblk = (n_edges + NT - 1) / NT;
    int nblk = (n_nodes + NT - 1) / NT;
    const int pers_blk = 2048;  // 8 blocks/CU x 256 CUs (thread-limit = 32 waves/CU)

    // CSR build
    zero_i32<<<nblk, NT, 0, stream>>>(cnt, n_nodes);
    hist_dst<<<eblk, NT, 0, stream>>>(cnt, dst, n_edges);
    scan_offsets<<<1, 1024, 0, stream>>>(cnt, row_off, cursor, n_nodes);
    edge_scatter<<<eblk, NT, 0, stream>>>(csr_src, cursor, src, dst, n_edges);

    // transposed WR copies + pool init
    wtrans<<<16, NT, 0, stream>>>(wr0t, Wr0);
    wtrans<<<16, NT, 0, stream>>>(wrt, Wr);
    pool_init<<<(128 * 64 + NT - 1) / NT, NT, 0, stream>>>(pooled, 128 * 64);

    sage_layer<<<pers_blk, NT, 0, stream>>>(bufA, pooled, x, row_off, csr_src, batch,
                                            Wl0, wr0t, bl0, n_nodes, 0);
    sage_layer<<<pers_blk, NT, 0, stream>>>(bufB, pooled, bufA, row_off, csr_src, batch,
                                            Wl, wrt, bl, n_nodes, 0);
    sage_layer<<<pers_blk, NT, 0, stream>>>(bufA, pooled, bufB, row_off, csr_src, batch,
                                            Wl, wrt, bl, n_nodes, 0);
    sage_layer<<<pers_blk, NT, 0, stream>>>(bufB, pooled, bufA, row_off, csr_src, batch,
                                            Wl, wrt, bl, n_nodes, 1);

    head<<<32, NT, 0, stream>>>((float*)d_out, pooled, W1, b1, W2, b2);
}